// Round 1
// 358.609 us; speedup vs baseline: 1.0048x; 1.0048x over previous
//
#include <hip/hip_runtime.h>

#define NNODES 50000
#define NEDGES 800000
#define NCLASS 40
#define NBLK_SCAN 196   // ceil(50000/256)
#define CNTB  3125      // NEDGES/256
#define PREPB 320       // 5*16384/256
#define WOUTB 24        // 48*128/256
#define GEMMB 782       // ceil(NNODES/64)
#define ATTN1B 391      // ceil(50000/128), one layer
#define AGGB  3125      // NNODES/16, 16 nodes per block (quarter-wave per node)

typedef _Float16 half8  __attribute__((ext_vector_type(8)));
typedef float    floatx4 __attribute__((ext_vector_type(4)));

// Cs transpose buffer: 64 rows x 136 halfs (stride 272B) + 64 floats of dinv
#define CSTR 136
#define SMEM_BYTES (64 * CSTR * 2 + 256)

__device__ __forceinline__ float fast_tanh(float x) {
    return 1.0f - 2.0f / (__expf(2.0f * x) + 1.0f);
}

// ---------------- fused pre-pass: count+rank | weights -> MFMA-fragment order | WoutT frag ----------
// Fragment layout (per 128x128 mat): element (n = ct*16 + l15, k = kk*32 + quad*8 + j)
// stored at ((kk*8 + ct)*64 + quad*16 + l15)*8 + j  -> a wave's B-frag load for (kk,ct)
// is lane-contiguous 1 KB. Kills the need for any LDS weight staging.
__global__ __launch_bounds__(256) void k_pre(const int* __restrict__ dst, int* __restrict__ cnt,
                                             int* __restrict__ rank,
                                             const float* __restrict__ convW, const float* __restrict__ W_att,
                                             _Float16* __restrict__ WT,
                                             const float* __restrict__ Wout, _Float16* __restrict__ WoutT) {
    int bid = blockIdx.x, tid = threadIdx.x;
    if (bid < CNTB) {
        int e = bid * 256 + tid;
        rank[e] = atomicAdd(&cnt[dst[e]], 1);
    } else if (bid < CNTB + PREPB) {
        int idx = (bid - CNTB) * 256 + tid;   // < 5*16384
        int mat = idx >> 14, rem = idx & 16383;
        int j = rem & 7, lane = (rem >> 3) & 63, tile = rem >> 9;
        int l15 = lane & 15, quad = lane >> 4;
        int ct = tile & 7, kk = tile >> 3;
        int n = ct * 16 + l15, k = kk * 32 + quad * 8 + j;
        const float* src = (mat < 4) ? (convW + mat * 16384) : W_att;
        WT[idx] = (_Float16)src[k * 128 + n];
    } else {
        int idx = (bid - CNTB - PREPB) * 256 + tid;   // < 12*512 = 6144
        int j = idx & 7, lane = (idx >> 3) & 63, tile = idx >> 9;
        int l15 = lane & 15, quad = lane >> 4;
        int ct = tile % 3, kk = tile / 3;
        int n = ct * 16 + l15, k = kk * 32 + quad * 8 + j;
        WoutT[idx] = (n < NCLASS) ? (_Float16)Wout[k * NCLASS + n] : (_Float16)0.f;
    }
}

__global__ __launch_bounds__(256) void k_bsum(const int* __restrict__ cnt, int* __restrict__ bsum) {
    int t = threadIdx.x, b = blockIdx.x;
    int i = b * 256 + t;
    int c = (i < NNODES) ? cnt[i] : 0;
    int v = c;
    v += __shfl_xor(v, 1);  v += __shfl_xor(v, 2);  v += __shfl_xor(v, 4);
    v += __shfl_xor(v, 8);  v += __shfl_xor(v, 16); v += __shfl_xor(v, 32);
    __shared__ int ws[4];
    if ((t & 63) == 0) ws[t >> 6] = v;
    __syncthreads();
    if (t == 0) bsum[b] = ws[0] + ws[1] + ws[2] + ws[3];
}

__global__ __launch_bounds__(256) void k_offsets(const int* __restrict__ cnt, const int* __restrict__ bsum,
                                                 int* __restrict__ offsets, float* __restrict__ dinv) {
    int t = threadIdx.x, b = blockIdx.x;
    int i = b * 256 + t;
    int c = (i < NNODES) ? cnt[i] : 0;
    int pv = (t < b) ? bsum[t] : 0;   // b <= 195 < 256
    int rv = pv;
    rv += __shfl_xor(rv, 1);  rv += __shfl_xor(rv, 2);  rv += __shfl_xor(rv, 4);
    rv += __shfl_xor(rv, 8);  rv += __shfl_xor(rv, 16); rv += __shfl_xor(rv, 32);
    __shared__ int wsum[4];
    __shared__ int part[256];
    if ((t & 63) == 0) wsum[t >> 6] = rv;
    part[t] = c;
    __syncthreads();
    int boff = wsum[0] + wsum[1] + wsum[2] + wsum[3];
#pragma unroll
    for (int d = 1; d < 256; d <<= 1) {
        int v = (t >= d) ? part[t - d] : 0;
        __syncthreads();
        part[t] += v;
        __syncthreads();
    }
    if (i < NNODES) {
        offsets[i] = boff + part[t] - c;
        dinv[i] = rsqrtf((float)c + 1.0f);
    }
    if (b == 0 && t == 0) offsets[NNODES] = NEDGES;
}

// ---------------- GEMM body: C[64,128] = (A @ W) * dinv; B-frags direct from global (frag layout) ----
// No W staging (zero reuse per block). smem = half Cs (17.4 KB) + 64-float dinv. 2 barriers.
template <bool F32A>
__device__ __forceinline__ void gemm_body(const void* __restrict__ Av, const _Float16* __restrict__ WTf,
                                          const float* __restrict__ dinv, _Float16* __restrict__ C,
                                          int m0, char* smem) {
    _Float16 (*Csh)[CSTR] = (_Float16 (*)[CSTR])smem;
    float* sdinv = (float*)(smem + 64 * CSTR * 2);
    int tid = threadIdx.x;
    int wave = tid >> 6, lane = tid & 63;
    int quad = lane >> 4, l15 = lane & 15;
    int ko = quad * 8;

    if (tid < 64) {
        int r = m0 + tid; if (r > NNODES - 1) r = NNODES - 1;
        sdinv[tid] = dinv[r];
    }

    floatx4 acc[4][2];
#pragma unroll
    for (int rt = 0; rt < 4; ++rt)
#pragma unroll
        for (int ct = 0; ct < 2; ++ct) acc[rt][ct] = (floatx4){0.f, 0.f, 0.f, 0.f};

#pragma unroll
    for (int kk = 0; kk < 4; ++kk) {
        half8 a[4], b[2];
#pragma unroll
        for (int rt = 0; rt < 4; ++rt) {
            int row = m0 + rt * 16 + l15;
            if (row > NNODES - 1) row = NNODES - 1;
            if (F32A) {
                const float* Ap = (const float*)Av + (size_t)row * 128 + kk * 32 + ko;
                float4 f0 = *(const float4*)Ap;
                float4 f1 = *(const float4*)(Ap + 4);
                a[rt] = (half8){(_Float16)f0.x, (_Float16)f0.y, (_Float16)f0.z, (_Float16)f0.w,
                                (_Float16)f1.x, (_Float16)f1.y, (_Float16)f1.z, (_Float16)f1.w};
            } else {
                a[rt] = *(const half8*)((const _Float16*)Av + (size_t)row * 128 + kk * 32 + ko);
            }
        }
#pragma unroll
        for (int ct = 0; ct < 2; ++ct)
            b[ct] = *(const half8*)&WTf[((kk * 8 + (wave * 2 + ct)) * 64 + lane) * 8];
#pragma unroll
        for (int rt = 0; rt < 4; ++rt)
#pragma unroll
            for (int ct = 0; ct < 2; ++ct)
                acc[rt][ct] = __builtin_amdgcn_mfma_f32_16x16x32_f16(a[rt], b[ct], acc[rt][ct], 0, 0, 0);
    }
    __syncthreads();   // sdinv visible

#pragma unroll
    for (int rt = 0; rt < 4; ++rt)
#pragma unroll
        for (int r = 0; r < 4; ++r) {
            float d = sdinv[rt * 16 + quad * 4 + r];
#pragma unroll
            for (int ct = 0; ct < 2; ++ct)
                Csh[rt * 16 + quad * 4 + r][wave * 32 + ct * 16 + l15] = (_Float16)(acc[rt][ct][r] * d);
        }
    __syncthreads();

    int row = tid >> 2, seg = tid & 3;
    int gm = m0 + row;
    if (gm < NNODES) {
#pragma unroll
        for (int j = 0; j < 4; ++j)
            *(half8*)(C + (size_t)gm * 128 + seg * 32 + j * 8) = *(const half8*)&Csh[row][seg * 32 + j * 8];
    }
}

// ---------------- attention body: 128 nodes/block, one layer slab; B-frags direct from global -------
__device__ __forceinline__ void attn_body(const _Float16* __restrict__ hs, const _Float16* __restrict__ WTatt,
                                          const float* __restrict__ a_att, float* __restrict__ scores,
                                          int layer, int abid) {
    int tid = threadIdx.x;
    int wave = tid >> 6, lane = tid & 63;
    int quad = lane >> 4, l15 = lane & 15;
    int ko = quad * 8;
    int nb = abid * 128 + wave * 32;              // 32 nodes per wave

    half8 af[2][4];                                // 2 row-tiles of 16 nodes
#pragma unroll
    for (int rt = 0; rt < 2; ++rt) {
        int node = nb + rt * 16 + l15;
        if (node > NNODES - 1) node = NNODES - 1;
        const _Float16* Ap = hs + (size_t)node * 128 + ko;
#pragma unroll
        for (int kk = 0; kk < 4; ++kk) af[rt][kk] = *(const half8*)(Ap + kk * 32);
    }

    float p[2][4];
#pragma unroll
    for (int rt = 0; rt < 2; ++rt)
#pragma unroll
        for (int r = 0; r < 4; ++r) p[rt][r] = 0.f;
#pragma unroll
    for (int ct = 0; ct < 8; ++ct) {
        half8 b[4];
#pragma unroll
        for (int kk = 0; kk < 4; ++kk)
            b[kk] = *(const half8*)&WTatt[((kk * 8 + ct) * 64 + lane) * 8];
        floatx4 acc[2];
#pragma unroll
        for (int rt = 0; rt < 2; ++rt) acc[rt] = (floatx4){0.f, 0.f, 0.f, 0.f};
#pragma unroll
        for (int kk = 0; kk < 4; ++kk)
#pragma unroll
            for (int rt = 0; rt < 2; ++rt)
                acc[rt] = __builtin_amdgcn_mfma_f32_16x16x32_f16(af[rt][kk], b[kk], acc[rt], 0, 0, 0);
        float av = a_att[ct * 16 + l15];
#pragma unroll
        for (int rt = 0; rt < 2; ++rt)
#pragma unroll
            for (int r = 0; r < 4; ++r) p[rt][r] += av * fast_tanh(acc[rt][r]);
    }
#pragma unroll
    for (int rt = 0; rt < 2; ++rt)
#pragma unroll
        for (int r = 0; r < 4; ++r) {
            float v = p[rt][r];
            v += __shfl_xor(v, 1); v += __shfl_xor(v, 2);
            v += __shfl_xor(v, 4); v += __shfl_xor(v, 8);
            if (l15 == 0) {
                int nd = nb + rt * 16 + quad * 4 + r;
                if (nd < NNODES) scores[(size_t)nd * 4 + layer] = v;
            }
        }
}

// ---------------- fused: GEMM layer l | attn on layer l-1 (both read-only on hh[l-1]) ----------------
__global__ __launch_bounds__(256) void k_gemmattn(const _Float16* __restrict__ A, const _Float16* __restrict__ WT,
                                                  const float* __restrict__ dinv, _Float16* __restrict__ C,
                                                  const _Float16* __restrict__ WTatt, const float* __restrict__ a_att,
                                                  float* __restrict__ scores, int layer) {
    __shared__ __align__(16) char smem[SMEM_BYTES];
    int bid = blockIdx.x;
    if (bid < GEMMB) {
        gemm_body<false>(A, WT, dinv, C, bid * 64, smem);
    } else {
        attn_body(A, WTatt, a_att, scores, layer, bid - GEMMB);
    }
}

// ---------------- standalone attn for the final layer ----------------
__global__ __launch_bounds__(256) void k_attn1(const _Float16* __restrict__ hs, const _Float16* __restrict__ WTatt,
                                               const float* __restrict__ a_att, float* __restrict__ scores,
                                               int layer) {
    attn_body(hs, WTatt, a_att, scores, layer, blockIdx.x);
}

// ---------------- fused: CSR fill (no atomic) | layer-0 GEMM straight from fp32 x ----------------
__global__ __launch_bounds__(256) void k_fillgemm(const int* __restrict__ src, const int* __restrict__ dst,
                                                  const int* __restrict__ offsets, const int* __restrict__ rank,
                                                  int* __restrict__ esrc,
                                                  const float* __restrict__ x, const _Float16* __restrict__ WT,
                                                  const float* __restrict__ dinv, _Float16* __restrict__ C) {
    __shared__ __align__(16) char smem[SMEM_BYTES];
    int bid = blockIdx.x;
    if (bid < GEMMB) {
        gemm_body<true>(x, WT, dinv, C, bid * 64, smem);
    } else {
        int e = (bid - GEMMB) * 256 + threadIdx.x;
        int d = dst[e];
        esrc[offsets[d] + rank[e]] = src[e];
    }
}

// ---------------- edge aggregation: 16 lanes/node, software-pipelined index loads ----------
// Per quarter-wave: one node. esrc for the NEXT 8 edges loads while current gathers are in flight,
// killing the serial esrc->gather 2-hop per iteration. Epilogue loads (dinv, self row) hoisted.
__global__ __launch_bounds__(256) void k_aggregate(const _Float16* __restrict__ hWs, const int* __restrict__ offsets,
                                                   const int* __restrict__ esrc, const float* __restrict__ dinv,
                                                   const float* __restrict__ bias, _Float16* __restrict__ outh) {
    __shared__ float bsh[128];
    int tid = threadIdx.x;
    if (tid < 128) bsh[tid] = bias[tid];
    __syncthreads();
    int l16 = tid & 15;
    int c8 = l16 * 8;
    int n = blockIdx.x * 16 + (tid >> 4);
    int beg = offsets[n], end = offsets[n + 1];
    // independent of the edge loop: issue early
    float dn = dinv[n];
    half8 sv = *(const half8*)(hWs + (size_t)n * 128 + c8);
    float4 b0 = *(const float4*)&bsh[c8];
    float4 b1 = *(const float4*)&bsh[c8 + 4];

    float a0 = 0.f, a1 = 0.f, a2 = 0.f, a3 = 0.f, a4 = 0.f, a5 = 0.f, a6 = 0.f, a7 = 0.f;
    int   idxA[8];
    float mskA[8];
#pragma unroll
    for (int i = 0; i < 8; ++i) {
        int ei = beg + i;
        int t = esrc[ei];            // esrc padded: speculative load in-bounds
        bool ok = ei < end;
        idxA[i] = ok ? t : n;
        mskA[i] = ok ? 1.f : 0.f;
    }
    for (int e = beg; e < end; e += 8) {
        half8 v[8];
#pragma unroll
        for (int i = 0; i < 8; ++i) v[i] = *(const half8*)(hWs + (size_t)idxA[i] * 128 + c8);
        int   idxB[8];
        float mskB[8];
#pragma unroll
        for (int i = 0; i < 8; ++i) {
            int ei = e + 8 + i;
            int t = esrc[ei];        // padded by +256 ints: always in-bounds
            bool ok = ei < end;
            idxB[i] = ok ? t : n;
            mskB[i] = ok ? 1.f : 0.f;
        }
#pragma unroll
        for (int i = 0; i < 8; ++i) {
            float m = mskA[i];
            a0 += m * (float)v[i][0]; a1 += m * (float)v[i][1];
            a2 += m * (float)v[i][2]; a3 += m * (float)v[i][3];
            a4 += m * (float)v[i][4]; a5 += m * (float)v[i][5];
            a6 += m * (float)v[i][6]; a7 += m * (float)v[i][7];
        }
#pragma unroll
        for (int i = 0; i < 8; ++i) { idxA[i] = idxB[i]; mskA[i] = mskB[i]; }
    }
    float r0 = (a0 + (float)sv[0]) * dn + b0.x;
    float r1 = (a1 + (float)sv[1]) * dn + b0.y;
    float r2 = (a2 + (float)sv[2]) * dn + b0.z;
    float r3 = (a3 + (float)sv[3]) * dn + b0.w;
    float r4 = (a4 + (float)sv[4]) * dn + b1.x;
    float r5 = (a5 + (float)sv[5]) * dn + b1.y;
    float r6 = (a6 + (float)sv[6]) * dn + b1.z;
    float r7 = (a7 + (float)sv[7]) * dn + b1.w;
    half8 o = {(_Float16)fmaxf(r0, 0.f), (_Float16)fmaxf(r1, 0.f),
               (_Float16)fmaxf(r2, 0.f), (_Float16)fmaxf(r3, 0.f),
               (_Float16)fmaxf(r4, 0.f), (_Float16)fmaxf(r5, 0.f),
               (_Float16)fmaxf(r6, 0.f), (_Float16)fmaxf(r7, 0.f)};
    *(half8*)(outh + (size_t)n * 128 + c8) = o;
}

// ---------------- softmax + layer-fuse (coalesced, all lanes) + MFMA out-projection ----------------
__global__ __launch_bounds__(256) void k_fuse_out(const _Float16* __restrict__ hbase, const float* __restrict__ scores,
                                                  const _Float16* __restrict__ WoutT, const float* __restrict__ bout,
                                                  float* __restrict__ out) {
    __shared__ __align__(16) _Float16 Fs[64][136];   // 17,408 B
    __shared__ float salpha[256];
    const size_t LSTR = (size_t)NNODES * 128;
    int tid = threadIdx.x;
    int n0 = blockIdx.x * 64;

    if (tid < 64) {
        int node = n0 + tid; if (node > NNODES - 1) node = NNODES - 1;
        float4 s = *(const float4*)(scores + (size_t)node * 4);
        float mx = fmaxf(fmaxf(s.x, s.y), fmaxf(s.z, s.w));
        float e0 = __expf(s.x - mx), e1 = __expf(s.y - mx), e2 = __expf(s.z - mx), e3 = __expf(s.w - mx);
        float inv = 1.0f / (e0 + e1 + e2 + e3);
        salpha[tid * 4 + 0] = e0 * inv; salpha[tid * 4 + 1] = e1 * inv;
        salpha[tid * 4 + 2] = e2 * inv; salpha[tid * 4 + 3] = e3 * inv;
    }
    __syncthreads();

    // fused = sum_l alpha_l * h_l; all 256 lanes, coalesced per (layer, j)
    {
        int no = tid >> 2, seg = tid & 3;
        int node = n0 + no; if (node > NNODES - 1) node = NNODES - 1;
        float al0 = salpha[no * 4 + 0], al1 = salpha[no * 4 + 1];
        float al2 = salpha[no * 4 + 2], al3 = salpha[no * 4 + 3];
        const _Float16* hp = hbase + (size_t)node * 128 + seg * 32;
#pragma unroll
        for (int j = 0; j < 4; ++j) {
            half8 h0 = *(const half8*)(hp + 0 * LSTR + j * 8);
            half8 h1 = *(const half8*)(hp + 1 * LSTR + j * 8);
            half8 h2 = *(const half8*)(hp + 2 * LSTR + j * 8);
            half8 h3 = *(const half8*)(hp + 3 * LSTR + j * 8);
            half8 f;
#pragma unroll
            for (int u = 0; u < 8; ++u)
                f[u] = (_Float16)(al0 * (float)h0[u] + al1 * (float)h1[u] +
                                  al2 * (float)h2[u] + al3 * (float)h3[u]);
            *(half8*)&Fs[no][seg * 32 + j * 8] = f;
        }
    }
    __syncthreads();

    // out-projection MFMA: 48 padded cols (3 frag tiles), masked fp32 write + bias
    int wave = tid >> 6, lane = tid & 63;
    int quad = lane >> 4, l15 = lane & 15;
    int ko = quad * 8;
    half8 ff[4];
    int frow = wave * 16 + l15;
#pragma unroll
    for (int kk = 0; kk < 4; ++kk) ff[kk] = *(const half8*)&Fs[frow][kk * 32 + ko];
#pragma unroll
    for (int ct = 0; ct < 3; ++ct) {
        half8 bw[4];
#pragma unroll
        for (int kk = 0; kk < 4; ++kk)
            bw[kk] = *(const half8*)(WoutT + ((kk * 3 + ct) * 64 + lane) * 8);
        floatx4 acc = (floatx4){0.f, 0.f, 0.f, 0.f};
#pragma unroll
        for (int kk = 0; kk < 4; ++kk)
            acc = __builtin_amdgcn_mfma_f32_16x16x32_f16(ff[kk], bw[kk], acc, 0, 0, 0);
        int col = ct * 16 + l15;
        if (col < NCLASS) {
            float bv = bout[col];
#pragma unroll
            for (int r = 0; r < 4; ++r) {
                int node = n0 + wave * 16 + quad * 4 + r;
                if (node < NNODES) out[(size_t)node * NCLASS + col] = acc[r] + bv;
            }
        }
    }
}

extern "C" void kernel_launch(void* const* d_in, const int* in_sizes, int n_in,
                              void* d_out, int out_size, void* d_ws, size_t ws_size,
                              hipStream_t stream) {
    const float* x     = (const float*)d_in[0];
    const int*   ei    = (const int*)d_in[1];
    const float* convW = (const float*)d_in[2];
    const float* convb = (const float*)d_in[3];
    const float* W_att = (const float*)d_in[4];
    const float* a_att = (const float*)d_in[5];
    const float* W_out = (const float*)d_in[6];
    const float* b_out = (const float*)d_in[7];
    float* out = (float*)d_out;

    char* ws = (char*)d_ws;
    size_t off = 0;
    auto take = [&](size_t nbytes) { char* p = ws + off; off += (nbytes + 255) & ~(size_t)255; return p; };
    float*     dinv    = (float*)take(NNODES * 4);
    int*       cnt     = (int*)take(NNODES * 4);
    int*       rank    = (int*)take(NEDGES * 4);
    int*       offsets = (int*)take((NNODES + 1) * 4);
    int*       bsum    = (int*)take(256 * 4);
    int*       esrc    = (int*)take(NEDGES * 4 + 256);   // +64 ints pad for speculative loads
    _Float16*  WoutT   = (_Float16*)take((size_t)48 * 128 * 2);
    float*     scores  = (float*)take(NNODES * 4 * 4);
    _Float16*  WT      = (_Float16*)take((size_t)5 * 128 * 128 * 2);
    _Float16*  hWs     = (_Float16*)take((size_t)NNODES * 128 * 2);
    _Float16*  hh[4];
    for (int l = 0; l < 4; ++l) hh[l] = (_Float16*)take((size_t)NNODES * 128 * 2);
    // NOTE: hh slabs are 12,800,000 B each (multiple of 256) -> contiguous; k_fuse_out relies on it.

    const int* src = ei;
    const int* dst = ei + NEDGES;

    hipMemsetAsync(cnt, 0, NNODES * 4, stream);
    k_pre<<<CNTB + PREPB + WOUTB, 256, 0, stream>>>(dst, cnt, rank, convW, W_att, WT, W_out, WoutT);
    k_bsum<<<NBLK_SCAN, 256, 0, stream>>>(cnt, bsum);
    k_offsets<<<NBLK_SCAN, 256, 0, stream>>>(cnt, bsum, offsets, dinv);
    k_fillgemm<<<GEMMB + CNTB, 256, 0, stream>>>(src, dst, offsets, rank, esrc, x, WT, dinv, hWs);

    k_aggregate<<<AGGB, 256, 0, stream>>>(hWs, offsets, esrc, dinv, convb + 0 * 128, hh[0]);
    for (int l = 1; l < 4; ++l) {
        // gemm layer l fused with attention scores for layer l-1 (both only read hh[l-1])
        k_gemmattn<<<GEMMB + ATTN1B, 256, 0, stream>>>(hh[l - 1], WT + l * 16384, dinv, hWs,
                                                       WT + 4 * 16384, a_att, scores, l - 1);
        k_aggregate<<<AGGB, 256, 0, stream>>>(hWs, offsets, esrc, dinv, convb + l * 128, hh[l]);
    }
    k_attn1<<<ATTN1B, 256, 0, stream>>>(hh[3], WT + 4 * 16384, a_att, scores, 3);
    k_fuse_out<<<GEMMB, 256, 0, stream>>>(hh[0], scores, WoutT, b_out, out);
}

// Round 2
// 314.854 us; speedup vs baseline: 1.1444x; 1.1390x over previous
//
#include <hip/hip_runtime.h>

#define NNODES 50000
#define NEDGES 800000
#define NCLASS 40
#define NBLK_SCAN 196   // ceil(50000/256)
#define CNTB  3125      // NEDGES/256
#define PREPB 320       // 5*16384/256
#define WOUTB 24        // 48*128/256
#define GEMMB 782       // ceil(NNODES/64)
#define XBLK  3125      // NNODES/16, 16 nodes per 128-thread layer block

typedef _Float16 half8  __attribute__((ext_vector_type(8)));
typedef float    floatx4 __attribute__((ext_vector_type(4)));

// Cs transpose buffer for the 64-row fp32-A gemm: 64 rows x 136 halfs + 64 floats of dinv
#define CSTR 136
#define SMEM_BYTES (64 * CSTR * 2 + 256)

__device__ __forceinline__ float fast_tanh(float x) {
    return 1.0f - 2.0f / (__expf(2.0f * x) + 1.0f);
}

// ---------------- fused pre-pass: count+rank | weights -> MFMA-fragment order | WoutT frag ----------
// Fragment layout (per 128x128 mat): element (n = ct*16 + l15, k = kk*32 + quad*8 + j)
// stored at ((kk*8 + ct)*64 + quad*16 + l15)*8 + j  -> a wave's B-frag load for (kk,ct)
// is lane-contiguous 1 KB.
__global__ __launch_bounds__(256) void k_pre(const int* __restrict__ dst, int* __restrict__ cnt,
                                             int* __restrict__ rank,
                                             const float* __restrict__ convW, const float* __restrict__ W_att,
                                             _Float16* __restrict__ WT,
                                             const float* __restrict__ Wout, _Float16* __restrict__ WoutT) {
    int bid = blockIdx.x, tid = threadIdx.x;
    if (bid < CNTB) {
        int e = bid * 256 + tid;
        rank[e] = atomicAdd(&cnt[dst[e]], 1);
    } else if (bid < CNTB + PREPB) {
        int idx = (bid - CNTB) * 256 + tid;   // < 5*16384
        int mat = idx >> 14, rem = idx & 16383;
        int j = rem & 7, lane = (rem >> 3) & 63, tile = rem >> 9;
        int l15 = lane & 15, quad = lane >> 4;
        int ct = tile & 7, kk = tile >> 3;
        int n = ct * 16 + l15, k = kk * 32 + quad * 8 + j;
        const float* src = (mat < 4) ? (convW + mat * 16384) : W_att;
        WT[idx] = (_Float16)src[k * 128 + n];
    } else {
        int idx = (bid - CNTB - PREPB) * 256 + tid;   // < 12*512 = 6144
        int j = idx & 7, lane = (idx >> 3) & 63, tile = idx >> 9;
        int l15 = lane & 15, quad = lane >> 4;
        int ct = tile % 3, kk = tile / 3;
        int n = ct * 16 + l15, k = kk * 32 + quad * 8 + j;
        WoutT[idx] = (n < NCLASS) ? (_Float16)Wout[k * NCLASS + n] : (_Float16)0.f;
    }
}

__global__ __launch_bounds__(256) void k_bsum(const int* __restrict__ cnt, int* __restrict__ bsum) {
    int t = threadIdx.x, b = blockIdx.x;
    int i = b * 256 + t;
    int c = (i < NNODES) ? cnt[i] : 0;
    int v = c;
    v += __shfl_xor(v, 1);  v += __shfl_xor(v, 2);  v += __shfl_xor(v, 4);
    v += __shfl_xor(v, 8);  v += __shfl_xor(v, 16); v += __shfl_xor(v, 32);
    __shared__ int ws[4];
    if ((t & 63) == 0) ws[t >> 6] = v;
    __syncthreads();
    if (t == 0) bsum[b] = ws[0] + ws[1] + ws[2] + ws[3];
}

__global__ __launch_bounds__(256) void k_offsets(const int* __restrict__ cnt, const int* __restrict__ bsum,
                                                 int* __restrict__ offsets, float* __restrict__ dinv) {
    int t = threadIdx.x, b = blockIdx.x;
    int i = b * 256 + t;
    int c = (i < NNODES) ? cnt[i] : 0;
    int pv = (t < b) ? bsum[t] : 0;   // b <= 195 < 256
    int rv = pv;
    rv += __shfl_xor(rv, 1);  rv += __shfl_xor(rv, 2);  rv += __shfl_xor(rv, 4);
    rv += __shfl_xor(rv, 8);  rv += __shfl_xor(rv, 16); rv += __shfl_xor(rv, 32);
    __shared__ int wsum[4];
    __shared__ int part[256];
    if ((t & 63) == 0) wsum[t >> 6] = rv;
    part[t] = c;
    __syncthreads();
    int boff = wsum[0] + wsum[1] + wsum[2] + wsum[3];
#pragma unroll
    for (int d = 1; d < 256; d <<= 1) {
        int v = (t >= d) ? part[t - d] : 0;
        __syncthreads();
        part[t] += v;
        __syncthreads();
    }
    if (i < NNODES) {
        offsets[i] = boff + part[t] - c;
        dinv[i] = rsqrtf((float)c + 1.0f);
    }
    if (b == 0 && t == 0) offsets[NNODES] = NEDGES;
}

// ---------------- 64-row GEMM body (layer-0 only, fp32 A): C = (A @ W) * dinv ----------------
__device__ __forceinline__ void gemm_body_f32(const float* __restrict__ Av, const _Float16* __restrict__ WTf,
                                              const float* __restrict__ dinv, _Float16* __restrict__ C,
                                              int m0, char* smem) {
    _Float16 (*Csh)[CSTR] = (_Float16 (*)[CSTR])smem;
    float* sdinv = (float*)(smem + 64 * CSTR * 2);
    int tid = threadIdx.x;
    int wave = tid >> 6, lane = tid & 63;
    int quad = lane >> 4, l15 = lane & 15;
    int ko = quad * 8;

    if (tid < 64) {
        int r = m0 + tid; if (r > NNODES - 1) r = NNODES - 1;
        sdinv[tid] = dinv[r];
    }

    floatx4 acc[4][2];
#pragma unroll
    for (int rt = 0; rt < 4; ++rt)
#pragma unroll
        for (int ct = 0; ct < 2; ++ct) acc[rt][ct] = (floatx4){0.f, 0.f, 0.f, 0.f};

#pragma unroll
    for (int kk = 0; kk < 4; ++kk) {
        half8 a[4], b[2];
#pragma unroll
        for (int rt = 0; rt < 4; ++rt) {
            int row = m0 + rt * 16 + l15;
            if (row > NNODES - 1) row = NNODES - 1;
            const float* Ap = Av + (size_t)row * 128 + kk * 32 + ko;
            float4 f0 = *(const float4*)Ap;
            float4 f1 = *(const float4*)(Ap + 4);
            a[rt] = (half8){(_Float16)f0.x, (_Float16)f0.y, (_Float16)f0.z, (_Float16)f0.w,
                            (_Float16)f1.x, (_Float16)f1.y, (_Float16)f1.z, (_Float16)f1.w};
        }
#pragma unroll
        for (int ct = 0; ct < 2; ++ct)
            b[ct] = *(const half8*)&WTf[((kk * 8 + (wave * 2 + ct)) * 64 + lane) * 8];
#pragma unroll
        for (int rt = 0; rt < 4; ++rt)
#pragma unroll
            for (int ct = 0; ct < 2; ++ct)
                acc[rt][ct] = __builtin_amdgcn_mfma_f32_16x16x32_f16(a[rt], b[ct], acc[rt][ct], 0, 0, 0);
    }
    __syncthreads();   // sdinv visible

#pragma unroll
    for (int rt = 0; rt < 4; ++rt)
#pragma unroll
        for (int r = 0; r < 4; ++r) {
            float d = sdinv[rt * 16 + quad * 4 + r];
#pragma unroll
            for (int ct = 0; ct < 2; ++ct)
                Csh[rt * 16 + quad * 4 + r][wave * 32 + ct * 16 + l15] = (_Float16)(acc[rt][ct][r] * d);
        }
    __syncthreads();

    int row = tid >> 2, seg = tid & 3;
    int gm = m0 + row;
    if (gm < NNODES) {
#pragma unroll
        for (int j = 0; j < 4; ++j)
            *(half8*)(C + (size_t)gm * 128 + seg * 32 + j * 8) = *(const half8*)&Csh[row][seg * 32 + j * 8];
    }
}

// ---------------- fused: CSR fill (no atomic) | layer-0 GEMM straight from fp32 x ----------------
__global__ __launch_bounds__(256) void k_fillgemm(const int* __restrict__ src, const int* __restrict__ dst,
                                                  const int* __restrict__ offsets, const int* __restrict__ rank,
                                                  int* __restrict__ esrc,
                                                  const float* __restrict__ x, const _Float16* __restrict__ WT,
                                                  const float* __restrict__ dinv, _Float16* __restrict__ C) {
    __shared__ __align__(16) char smem[SMEM_BYTES];
    int bid = blockIdx.x;
    if (bid < GEMMB) {
        gemm_body_f32(x, WT, dinv, C, bid * 64, smem);
    } else {
        int e = (bid - GEMMB) * 256 + threadIdx.x;
        int d = dst[e];
        esrc[offsets[d] + rank[e]] = src[e];
    }
}

// ---------------- fused layer kernel: aggregate(l) | attention(l) | gemm(l+1) ----------------
// Block = 128 threads (2 waves), 16 nodes. Aggregation: 8 lanes/node, 4-deep pipelined gathers.
// Post-relu h kept in LDS -> attention and next-layer GEMM read it from LDS (no global re-read).
// Gathers read hin; gemm writes hout (ping-pong buffers, so no intra-kernel race).
template <bool HAS_GEMM>
__global__ __launch_bounds__(128) void k_layer(const _Float16* __restrict__ hin,
                                               const int* __restrict__ offsets, const int* __restrict__ esrc,
                                               const float* __restrict__ dinv, const float* __restrict__ bias,
                                               _Float16* __restrict__ hh,
                                               const _Float16* __restrict__ WTatt, const float* __restrict__ a_att,
                                               float* __restrict__ scores, int layer,
                                               const _Float16* __restrict__ WTnext, _Float16* __restrict__ hout) {
    __shared__ __align__(16) _Float16 h[16][CSTR];   // 4,352 B; reused as Cs in the gemm epilogue
    __shared__ float bsh[128];
    __shared__ float sdv[16];
    __shared__ float pp[2][16];
    int tid = threadIdx.x;
    bsh[tid] = bias[tid];
    int wave = tid >> 6, lane = tid & 63;
    int n0 = blockIdx.x * 16;

    // ---- P1: aggregate 16 nodes (8 lanes per node, 16 channels per lane) ----
    {
        int nl = tid >> 3;               // 0..15
        int cl = tid & 7;
        int c16 = cl * 16;
        int n = n0 + nl;                 // XBLK*16 == NNODES: always valid
        int beg = offsets[n], end = offsets[n + 1];
        float dn = dinv[n];
        const _Float16* sp = hin + (size_t)n * 128 + c16;
        half8 sv0 = *(const half8*)sp;
        half8 sv1 = *(const half8*)(sp + 8);

        float a[16];
#pragma unroll
        for (int u = 0; u < 16; ++u) a[u] = 0.f;

        int idxA[4]; float mskA[4];
#pragma unroll
        for (int i = 0; i < 4; ++i) {
            int ei = beg + i;
            int t = esrc[ei];            // esrc padded: speculative load in-bounds
            bool ok = ei < end;
            idxA[i] = ok ? t : n;
            mskA[i] = ok ? 1.f : 0.f;
        }
        for (int e = beg; e < end; e += 4) {
            half8 v0[4], v1[4];
#pragma unroll
            for (int i = 0; i < 4; ++i) {
                const _Float16* p = hin + (size_t)idxA[i] * 128 + c16;
                v0[i] = *(const half8*)p;
                v1[i] = *(const half8*)(p + 8);
            }
            int idxB[4]; float mskB[4];
#pragma unroll
            for (int i = 0; i < 4; ++i) {
                int ei = e + 4 + i;
                int t = esrc[ei];        // padded: always in-bounds
                bool ok = ei < end;
                idxB[i] = ok ? t : n;
                mskB[i] = ok ? 1.f : 0.f;
            }
#pragma unroll
            for (int i = 0; i < 4; ++i) {
                float m = mskA[i];
#pragma unroll
                for (int u = 0; u < 8; ++u) {
                    a[u]     += m * (float)v0[i][u];
                    a[8 + u] += m * (float)v1[i][u];
                }
            }
#pragma unroll
            for (int i = 0; i < 4; ++i) { idxA[i] = idxB[i]; mskA[i] = mskB[i]; }
        }
        __syncthreads();   // bsh ready
        half8 o0, o1;
#pragma unroll
        for (int u = 0; u < 8; ++u) {
            float r0 = (a[u]     + (float)sv0[u]) * dn + bsh[c16 + u];
            float r1 = (a[8 + u] + (float)sv1[u]) * dn + bsh[c16 + 8 + u];
            o0[u] = (_Float16)fmaxf(r0, 0.f);
            o1[u] = (_Float16)fmaxf(r1, 0.f);
        }
        *(half8*)(hh + (size_t)n * 128 + c16)     = o0;
        *(half8*)(hh + (size_t)n * 128 + c16 + 8) = o1;
        *(half8*)&h[nl][c16]     = o0;
        *(half8*)&h[nl][c16 + 8] = o1;
        if (cl == 0) sdv[nl] = dn;
    }
    __syncthreads();

    int quad = lane >> 4, l15 = lane & 15;
    int ko = quad * 8;
    half8 af[4];                          // A-frags of the 16 rows, shared by attn + gemm
#pragma unroll
    for (int kk = 0; kk < 4; ++kk) af[kk] = *(const half8*)&h[l15][kk * 32 + ko];

    // ---- P2: attention scores for these 16 nodes (wave w handles cols w*64..w*64+63) ----
    {
        float p[4] = {0.f, 0.f, 0.f, 0.f};
#pragma unroll
        for (int c2 = 0; c2 < 4; ++c2) {
            int ct = wave * 4 + c2;
            half8 b[4];
#pragma unroll
            for (int kk = 0; kk < 4; ++kk)
                b[kk] = *(const half8*)&WTatt[((kk * 8 + ct) * 64 + lane) * 8];
            floatx4 acc = (floatx4){0.f, 0.f, 0.f, 0.f};
#pragma unroll
            for (int kk = 0; kk < 4; ++kk)
                acc = __builtin_amdgcn_mfma_f32_16x16x32_f16(af[kk], b[kk], acc, 0, 0, 0);
            float av = a_att[ct * 16 + l15];
#pragma unroll
            for (int r = 0; r < 4; ++r) p[r] += av * fast_tanh(acc[r]);
        }
#pragma unroll
        for (int r = 0; r < 4; ++r) {
            float v = p[r];
            v += __shfl_xor(v, 1); v += __shfl_xor(v, 2);
            v += __shfl_xor(v, 4); v += __shfl_xor(v, 8);
            if (l15 == 0) pp[wave][quad * 4 + r] = v;
        }
    }
    __syncthreads();
    if (tid < 16) scores[(size_t)(n0 + tid) * 4 + layer] = pp[0][tid] + pp[1][tid];

    // ---- P3: next-layer GEMM, A from LDS ----
    if (HAS_GEMM) {
        floatx4 acc[4];
#pragma unroll
        for (int c2 = 0; c2 < 4; ++c2) acc[c2] = (floatx4){0.f, 0.f, 0.f, 0.f};
#pragma unroll
        for (int c2 = 0; c2 < 4; ++c2) {
            int ct = wave * 4 + c2;
#pragma unroll
            for (int kk = 0; kk < 4; ++kk) {
                half8 b = *(const half8*)&WTnext[((kk * 8 + ct) * 64 + lane) * 8];
                acc[c2] = __builtin_amdgcn_mfma_f32_16x16x32_f16(af[kk], b, acc[c2], 0, 0, 0);
            }
        }
        __syncthreads();   // everyone done reading h before it becomes Cs
#pragma unroll
        for (int c2 = 0; c2 < 4; ++c2) {
            int col = wave * 64 + c2 * 16 + l15;
#pragma unroll
            for (int r = 0; r < 4; ++r) {
                int row = quad * 4 + r;
                h[row][col] = (_Float16)(acc[c2][r] * sdv[row]);
            }
        }
        __syncthreads();
        int row = tid >> 3, seg = tid & 7;
        int gm = n0 + row;
        *(half8*)(hout + (size_t)gm * 128 + seg * 16)     = *(const half8*)&h[row][seg * 16];
        *(half8*)(hout + (size_t)gm * 128 + seg * 16 + 8) = *(const half8*)&h[row][seg * 16 + 8];
    }
}

// ---------------- softmax + layer-fuse (coalesced, all lanes) + MFMA out-projection ----------------
__global__ __launch_bounds__(256) void k_fuse_out(const _Float16* __restrict__ hbase, const float* __restrict__ scores,
                                                  const _Float16* __restrict__ WoutT, const float* __restrict__ bout,
                                                  float* __restrict__ out) {
    __shared__ __align__(16) _Float16 Fs[64][136];   // 17,408 B
    __shared__ float salpha[256];
    const size_t LSTR = (size_t)NNODES * 128;
    int tid = threadIdx.x;
    int n0 = blockIdx.x * 64;

    if (tid < 64) {
        int node = n0 + tid; if (node > NNODES - 1) node = NNODES - 1;
        float4 s = *(const float4*)(scores + (size_t)node * 4);
        float mx = fmaxf(fmaxf(s.x, s.y), fmaxf(s.z, s.w));
        float e0 = __expf(s.x - mx), e1 = __expf(s.y - mx), e2 = __expf(s.z - mx), e3 = __expf(s.w - mx);
        float inv = 1.0f / (e0 + e1 + e2 + e3);
        salpha[tid * 4 + 0] = e0 * inv; salpha[tid * 4 + 1] = e1 * inv;
        salpha[tid * 4 + 2] = e2 * inv; salpha[tid * 4 + 3] = e3 * inv;
    }
    __syncthreads();

    // fused = sum_l alpha_l * h_l; all 256 lanes, coalesced per (layer, j)
    {
        int no = tid >> 2, seg = tid & 3;
        int node = n0 + no; if (node > NNODES - 1) node = NNODES - 1;
        float al0 = salpha[no * 4 + 0], al1 = salpha[no * 4 + 1];
        float al2 = salpha[no * 4 + 2], al3 = salpha[no * 4 + 3];
        const _Float16* hp = hbase + (size_t)node * 128 + seg * 32;
#pragma unroll
        for (int j = 0; j < 4; ++j) {
            half8 h0 = *(const half8*)(hp + 0 * LSTR + j * 8);
            half8 h1 = *(const half8*)(hp + 1 * LSTR + j * 8);
            half8 h2 = *(const half8*)(hp + 2 * LSTR + j * 8);
            half8 h3 = *(const half8*)(hp + 3 * LSTR + j * 8);
            half8 f;
#pragma unroll
            for (int u = 0; u < 8; ++u)
                f[u] = (_Float16)(al0 * (float)h0[u] + al1 * (float)h1[u] +
                                  al2 * (float)h2[u] + al3 * (float)h3[u]);
            *(half8*)&Fs[no][seg * 32 + j * 8] = f;
        }
    }
    __syncthreads();

    // out-projection MFMA: 48 padded cols (3 frag tiles), masked fp32 write + bias
    int wave = tid >> 6, lane = tid & 63;
    int quad = lane >> 4, l15 = lane & 15;
    int ko = quad * 8;
    half8 ff[4];
    int frow = wave * 16 + l15;
#pragma unroll
    for (int kk = 0; kk < 4; ++kk) ff[kk] = *(const half8*)&Fs[frow][kk * 32 + ko];
#pragma unroll
    for (int ct = 0; ct < 3; ++ct) {
        half8 bw[4];
#pragma unroll
        for (int kk = 0; kk < 4; ++kk)
            bw[kk] = *(const half8*)(WoutT + ((kk * 3 + ct) * 64 + lane) * 8);
        floatx4 acc = (floatx4){0.f, 0.f, 0.f, 0.f};
#pragma unroll
        for (int kk = 0; kk < 4; ++kk)
            acc = __builtin_amdgcn_mfma_f32_16x16x32_f16(ff[kk], bw[kk], acc, 0, 0, 0);
        int col = ct * 16 + l15;
        if (col < NCLASS) {
            float bv = bout[col];
#pragma unroll
            for (int r = 0; r < 4; ++r) {
                int node = n0 + wave * 16 + quad * 4 + r;
                if (node < NNODES) out[(size_t)node * NCLASS + col] = acc[r] + bv;
            }
        }
    }
}

extern "C" void kernel_launch(void* const* d_in, const int* in_sizes, int n_in,
                              void* d_out, int out_size, void* d_ws, size_t ws_size,
                              hipStream_t stream) {
    const float* x     = (const float*)d_in[0];
    const int*   ei    = (const int*)d_in[1];
    const float* convW = (const float*)d_in[2];
    const float* convb = (const float*)d_in[3];
    const float* W_att = (const float*)d_in[4];
    const float* a_att = (const float*)d_in[5];
    const float* W_out = (const float*)d_in[6];
    const float* b_out = (const float*)d_in[7];
    float* out = (float*)d_out;

    char* ws = (char*)d_ws;
    size_t off = 0;
    auto take = [&](size_t nbytes) { char* p = ws + off; off += (nbytes + 255) & ~(size_t)255; return p; };
    float*     dinv    = (float*)take(NNODES * 4);
    int*       cnt     = (int*)take(NNODES * 4);
    int*       rank    = (int*)take(NEDGES * 4);
    int*       offsets = (int*)take((NNODES + 1) * 4);
    int*       bsum    = (int*)take(256 * 4);
    int*       esrc    = (int*)take(NEDGES * 4 + 256);   // +64 ints pad for speculative loads
    _Float16*  WoutT   = (_Float16*)take((size_t)48 * 128 * 2);
    float*     scores  = (float*)take(NNODES * 4 * 4);
    _Float16*  WT      = (_Float16*)take((size_t)5 * 128 * 128 * 2);
    _Float16*  hWsA    = (_Float16*)take((size_t)NNODES * 128 * 2);
    _Float16*  hh[4];
    for (int l = 0; l < 4; ++l) hh[l] = (_Float16*)take((size_t)NNODES * 128 * 2);
    // NOTE: hh slabs are 12,800,000 B each (multiple of 256) -> contiguous; k_fuse_out relies on it.
    _Float16*  hWsB    = (_Float16*)take((size_t)NNODES * 128 * 2);

    const int* src = ei;
    const int* dst = ei + NEDGES;

    hipMemsetAsync(cnt, 0, NNODES * 4, stream);
    k_pre<<<CNTB + PREPB + WOUTB, 256, 0, stream>>>(dst, cnt, rank, convW, W_att, WT, W_out, WoutT);
    k_bsum<<<NBLK_SCAN, 256, 0, stream>>>(cnt, bsum);
    k_offsets<<<NBLK_SCAN, 256, 0, stream>>>(cnt, bsum, offsets, dinv);
    k_fillgemm<<<GEMMB + CNTB, 256, 0, stream>>>(src, dst, offsets, rank, esrc, x, WT, dinv, hWsA);

    // layer kernels: aggregate(l) + attention(l) + gemm(l+1); hWs ping-pongs A->B->A->B
    k_layer<true><<<XBLK, 128, 0, stream>>>(hWsA, offsets, esrc, dinv, convb + 0 * 128, hh[0],
                                            WT + 4 * 16384, a_att, scores, 0, WT + 1 * 16384, hWsB);
    k_layer<true><<<XBLK, 128, 0, stream>>>(hWsB, offsets, esrc, dinv, convb + 1 * 128, hh[1],
                                            WT + 4 * 16384, a_att, scores, 1, WT + 2 * 16384, hWsA);
    k_layer<true><<<XBLK, 128, 0, stream>>>(hWsA, offsets, esrc, dinv, convb + 2 * 128, hh[2],
                                            WT + 4 * 16384, a_att, scores, 2, WT + 3 * 16384, hWsB);
    k_layer<false><<<XBLK, 128, 0, stream>>>(hWsB, offsets, esrc, dinv, convb + 3 * 128, hh[3],
                                             WT + 4 * 16384, a_att, scores, 3, (const _Float16*)nullptr,
                                             (_Float16*)nullptr);
    k_fuse_out<<<GEMMB, 256, 0, stream>>>(hh[0], scores, WoutT, b_out, out);
}